// Round 15
// baseline (529.602 us; speedup 1.0000x reference)
//
#include <hip/hip_runtime.h>
#include <hip/hip_bf16.h>
#include <math.h>

#define HC 256
#define NH 8
#define NEG_SLOPE 0.2f
#define CHW 64   // edges per chunk per wave (aggregation)
#define LDA 136  // LDS row stride in u16 (272 B)

typedef unsigned short u16;
typedef __attribute__((ext_vector_type(8))) short bf16x8;
typedef __attribute__((ext_vector_type(4))) float f32x4;

__device__ __forceinline__ u16 f2bf(float f) {
    unsigned int u = __float_as_uint(f);
    u += 0x7FFFu + ((u >> 16) & 1u);
    return (u16)(u >> 16);
}
__device__ __forceinline__ float bf2f(u16 s) {
    return __uint_as_float(((unsigned int)s) << 16);
}
__device__ __forceinline__ f32x4 bf4f(ushort4 v) {
    f32x4 r;
    r[0] = bf2f(v.x); r[1] = bf2f(v.y); r[2] = bf2f(v.z); r[3] = bf2f(v.w);
    return r;
}

// raw barrier: own LDS writes drained -> all-wave barrier -> no read hoisting.
#define BAR_LDS()                                                  \
    do {                                                           \
        asm volatile("s_waitcnt lgkmcnt(0)" ::: "memory");         \
        __builtin_amdgcn_s_barrier();                              \
        __builtin_amdgcn_sched_barrier(0);                         \
    } while (0)

// ---------------------------------------------------------------------------
// pack B (fp32 [K x 256]) -> hi/lo, fragment-major
// ---------------------------------------------------------------------------
__global__ __launch_bounds__(256) void pack_b_split(const float* __restrict__ B, int K,
                                                    u16* __restrict__ Bh,
                                                    u16* __restrict__ Bl) {
    const int g = blockIdx.x * 256 + threadIdx.x;
    const int lane = g & 63;
    const int f = (g >> 6) & 15;
    const int kt = g >> 10;
    const int col = f * 16 + (lane & 15);
    const int k0 = kt * 32 + (lane >> 4) * 8;
    bf16x8 hv, lv;
#pragma unroll
    for (int e = 0; e < 8; e++) {
        const float v = B[(size_t)(k0 + e) * HC + col];
        const u16 h = f2bf(v);
        hv[e] = (short)h;
        lv[e] = (short)f2bf(v - bf2f(h));
    }
    const size_t off = (size_t)g * 8;
    *(bf16x8*)(Bh + off) = hv;
    *(bf16x8*)(Bl + off) = lv;
}

// ---------------------------------------------------------------------------
// Fused MFMA GEMM: C = Ah*(Bh + Bl). Round-14 structure + PER-BLOCK PHASE
// ROTATION of the 128-k group order: block b processes groups (g + b) % NG4,
// de-phasing the B-fragment reads so concurrent blocks hit different L2
// slices (anti-hot-lining). B loads are issued inside each group.
// Requires K % 128 == 0 (K = 1280 or 256).
// ---------------------------------------------------------------------------
__global__ __launch_bounds__(256) void gemm_fused_split(
    const float* __restrict__ A,
    const u16* __restrict__ Bh, const u16* __restrict__ Bl,
    float* __restrict__ C, int M, int K) {
    __shared__ u16 ldsA[2][64 * LDA];   // 2 x 17.4 KB
    const int tid = threadIdx.x;
    const int wid = tid >> 6;        // 0..3
    const int lane = tid & 63;
    const int rowblk = blockIdx.x;
    const int NG4 = K >> 7;          // 128-k groups (10 or 2)
    const int rot = rowblk % NG4;    // per-block phase rotation

    f32x4 acc[4][4];
#pragma unroll
    for (int i = 0; i < 4; i++)
#pragma unroll
        for (int j = 0; j < 4; j++) acc[i][j] = (f32x4)0.f;

    // staging map: thread t -> row t>>2, 32 consecutive floats at (t&3)*32
    const int srow = tid >> 2;
    const int scc = (tid & 3) * 32;
    const int grow = rowblk * 64 + srow;
    const float* aptr = (grow < M) ? (A + (size_t)grow * K + scc) : nullptr;
    const int woff = srow * LDA + scc;

    float4 pf[8];
    auto loadAg = [&](int gg) {   // gg = physical group index
#pragma unroll
        for (int q = 0; q < 8; q++) {
            pf[q] = make_float4(0.f, 0.f, 0.f, 0.f);
            if (aptr) pf[q] = *(const float4*)(aptr + gg * 128 + q * 4);
        }
    };
    auto stageg = [&](int buf) {
#pragma unroll
        for (int p = 0; p < 4; p++) {
            const float vv[8] = {pf[2 * p].x,     pf[2 * p].y,
                                 pf[2 * p].z,     pf[2 * p].w,
                                 pf[2 * p + 1].x, pf[2 * p + 1].y,
                                 pf[2 * p + 1].z, pf[2 * p + 1].w};
            bf16x8 hv;
#pragma unroll
            for (int e = 0; e < 8; e++) hv[e] = (short)f2bf(vv[e]);
            *(bf16x8*)&ldsA[buf][woff + p * 8] = hv;
        }
    };
    auto readA = [&](int buf, int kk, bf16x8* ah) {
#pragma unroll
        for (int i = 0; i < 4; i++)
            ah[i] = *(const bf16x8*)&ldsA[buf][(i * 16 + (lane & 15)) * LDA +
                                              kk * 32 + (lane >> 4) * 8];
    };
    auto loadB = [&](int kt, bf16x8* bh, bf16x8* bl) {
        const u16* bHp = Bh + ((size_t)kt * 16 + wid * 4) * 512 + lane * 8;
        const u16* bLp = Bl + ((size_t)kt * 16 + wid * 4) * 512 + lane * 8;
#pragma unroll
        for (int j = 0; j < 4; j++) {
            bh[j] = *(const bf16x8*)(bHp + j * 512);
            bl[j] = *(const bf16x8*)(bLp + j * 512);
        }
    };
    auto mfma_tile = [&](const bf16x8* ah, const bf16x8* bh, const bf16x8* bl) {
#pragma unroll
        for (int i = 0; i < 4; i++)
#pragma unroll
            for (int j = 0; j < 4; j++) {
                acc[i][j] = __builtin_amdgcn_mfma_f32_16x16x32_bf16(ah[i], bh[j], acc[i][j], 0, 0, 0);
                acc[i][j] = __builtin_amdgcn_mfma_f32_16x16x32_bf16(ah[i], bl[j], acc[i][j], 0, 0, 0);
            }
    };

    // preamble: rotated group 0 staged in buf 0; rotated group 1 in pf (in flight)
    loadAg(rot);
    stageg(0);
    if (NG4 > 1) loadAg((rot + 1) % NG4);
    BAR_LDS();

    bf16x8 b0h[4], b0l[4], b1h[4], b1l[4];

    int cur = 0;
    for (int g = 0; g < NG4; ++g) {
        const int gg = (g + rot) % NG4;          // group staged in buf cur
        // stage rotated group g+1 (pf) into other buffer, issue loads for g+2
        if (g + 1 < NG4) stageg(cur ^ 1);
        if (g + 2 < NG4) loadAg((g + 2 + rot) % NG4);

        const int kt0 = gg * 4;                  // kt0..kt0+3 all < KT
        loadB(kt0, b0h, b0l);
        {   // kk = 0 (set 0); prefetch kt0+1 -> set 1
            loadB(kt0 + 1, b1h, b1l);
            bf16x8 ah[4];
            readA(cur, 0, ah);
            mfma_tile(ah, b0h, b0l);
        }
        {   // kk = 1 (set 1); prefetch kt0+2 -> set 0
            loadB(kt0 + 2, b0h, b0l);
            bf16x8 ah[4];
            readA(cur, 1, ah);
            mfma_tile(ah, b1h, b1l);
        }
        {   // kk = 2 (set 0); prefetch kt0+3 -> set 1
            loadB(kt0 + 3, b1h, b1l);
            bf16x8 ah[4];
            readA(cur, 2, ah);
            mfma_tile(ah, b0h, b0l);
        }
        {   // kk = 3 (set 1)
            bf16x8 ah[4];
            readA(cur, 3, ah);
            mfma_tile(ah, b1h, b1l);
        }
        BAR_LDS();
        cur ^= 1;
    }

    // epilogue: C/D layout col = lane&15, row = (lane>>4)*4 + r
    const int r0 = rowblk * 64;
    const int colb = wid * 64 + (lane & 15);
#pragma unroll
    for (int i = 0; i < 4; i++) {
#pragma unroll
        for (int r = 0; r < 4; r++) {
            const int row = r0 + i * 16 + (lane >> 4) * 4 + r;
            if (row < M) {
#pragma unroll
                for (int j = 0; j < 4; j++)
                    C[(size_t)row * HC + colb + j * 16] = acc[i][j][r];
            }
        }
    }
}

// ---------------------------------------------------------------------------
// Per-node attention coefficients + bf16 copy of h for the gather
// ---------------------------------------------------------------------------
__global__ __launch_bounds__(256) void attn_coef(const float* __restrict__ h,
                                                 const float* __restrict__ att_s,
                                                 const float* __restrict__ att_d,
                                                 float* __restrict__ a_src,
                                                 float* __restrict__ a_dst,
                                                 u16* __restrict__ h_bf) {
    const int n = blockIdx.x;
    const int tid = threadIdx.x;
    const float hv = h[(size_t)n * HC + tid];
    h_bf[(size_t)n * HC + tid] = f2bf(hv);
    float p = hv * att_s[tid];
    float q = hv * att_d[tid];
#pragma unroll
    for (int m = 16; m >= 1; m >>= 1) {
        p += __shfl_xor(p, m);
        q += __shfl_xor(q, m);
    }
    if ((tid & 31) == 0) {
        a_src[n * NH + (tid >> 5)] = p;
        a_dst[n * NH + (tid >> 5)] = q;
    }
}

// ---------------------------------------------------------------------------
// CSR build: count, two-level scan, scatter (stores resolved src ids)
// ---------------------------------------------------------------------------
__global__ void count_deg(const int* __restrict__ dst, int E, int ET, int* __restrict__ deg) {
    const int e = blockIdx.x * blockDim.x + threadIdx.x;
    if (e >= ET) return;
    const int d = (e < E) ? dst[e] : (e - E);
    atomicAdd(&deg[d], 1);
}

__global__ __launch_bounds__(256) void scan_block(const int* __restrict__ deg,
                                                  int* __restrict__ row_ptr,
                                                  int* __restrict__ partials, int N) {
    __shared__ int sd[256];
    const int tid = threadIdx.x;
    const int base = blockIdx.x * 1024 + tid * 4;
    int v0 = (base + 0 < N) ? deg[base + 0] : 0;
    int v1 = (base + 1 < N) ? deg[base + 1] : 0;
    int v2 = (base + 2 < N) ? deg[base + 2] : 0;
    int v3 = (base + 3 < N) ? deg[base + 3] : 0;
    const int tsum = v0 + v1 + v2 + v3;
    sd[tid] = tsum;
    __syncthreads();
    int run = tsum;
    for (int off = 1; off < 256; off <<= 1) {
        int t = 0;
        if (tid >= off) t = sd[tid - off];
        __syncthreads();
        run += t;
        sd[tid] = run;
        __syncthreads();
    }
    const int excl = run - tsum;
    int s0 = excl + v0, s1 = s0 + v1, s2 = s1 + v2, s3 = s2 + v3;
    if (base + 0 < N) row_ptr[base + 1] = s0;
    if (base + 1 < N) row_ptr[base + 2] = s1;
    if (base + 2 < N) row_ptr[base + 3] = s2;
    if (base + 3 < N) row_ptr[base + 4] = s3;
    if (tid == 255) partials[blockIdx.x] = run;
}

__global__ __launch_bounds__(1024) void scan_partials(int* __restrict__ partials, int nb) {
    __shared__ int sd[1024];
    const int tid = threadIdx.x;
    int v = (tid < nb) ? partials[tid] : 0;
    sd[tid] = v;
    __syncthreads();
    int run = v;
    for (int off = 1; off < 1024; off <<= 1) {
        int t = 0;
        if (tid >= off) t = sd[tid - off];
        __syncthreads();
        run += t;
        sd[tid] = run;
        __syncthreads();
    }
    if (tid < nb) partials[tid] = run - v;  // exclusive
}

__global__ __launch_bounds__(256) void scan_add(int* __restrict__ row_ptr,
                                                const int* __restrict__ partials, int N) {
    const int i = blockIdx.x * 256 + threadIdx.x;
    if (i == 0) row_ptr[0] = 0;
    if (i < N) row_ptr[i + 1] += partials[i >> 10];
}

__global__ void scatter_edges(const int* __restrict__ src_in, const int* __restrict__ dst,
                              int E, int ET, const int* __restrict__ row_ptr,
                              int* __restrict__ cursor, int* __restrict__ esrc) {
    const int e = blockIdx.x * blockDim.x + threadIdx.x;
    if (e >= ET) return;
    const int d = (e < E) ? dst[e] : (e - E);
    const int s = (e < E) ? src_in[e] : (e - E);
    const int pos = atomicAdd(&cursor[d], 1);
    esrc[row_ptr[d] + pos] = s;
}

// ---------------------------------------------------------------------------
// GAT aggregation, one WAVE per dst node. Gather reads bf16 h rows (512B/row).
// ---------------------------------------------------------------------------
__global__ __launch_bounds__(256) void gat_aggregate_wave(
    const u16* __restrict__ h_bf, const float* __restrict__ a_src,
    const float* __restrict__ a_dst, const int* __restrict__ row_ptr,
    const int* __restrict__ esrc, const float* __restrict__ bias,
    float* __restrict__ out, int N) {
    __shared__ int   s_src[4][CHW];
    __shared__ float s_ev[4][CHW][NH];

    const int tid = threadIdx.x;
    const int wv = tid >> 6;
    const int lane = tid & 63;
    const int n = blockIdx.x * 4 + wv;
    if (n >= N) return;

    const int beg = row_ptr[n];
    const int deg = row_ptr[n + 1] - beg;
    const int jj = lane >> 3;   // edge slot 0..7
    const int hh = lane & 7;    // head for softmax lanes
    const int g4 = lane >> 3;   // head for gather features

    const float adh = a_dst[n * NH + hh];
    float m_run = -1e30f, d_run = 0.f;
    f32x4 acc = (f32x4)0.f;

    for (int c0 = 0; c0 < deg; c0 += CHW) {
        const int chlen = min(CHW, deg - c0);

        float lmax = -1e30f;
        for (int p = 0; p < chlen; p += 8) {
            const int j = p + jj;
            if (j < chlen) {
                const int s = esrc[beg + c0 + j];
                if (hh == 0) s_src[wv][j] = s;
                float v = a_src[s * NH + hh] + adh;
                v = (v > 0.f) ? v : NEG_SLOPE * v;
                s_ev[wv][j][hh] = v;
                lmax = fmaxf(lmax, v);
            }
        }
        lmax = fmaxf(lmax, __shfl_xor(lmax, 8));
        lmax = fmaxf(lmax, __shfl_xor(lmax, 16));
        lmax = fmaxf(lmax, __shfl_xor(lmax, 32));
        const float mo = m_run;
        const float mn = fmaxf(mo, lmax);
        const float scl = __expf(mo - mn);
        m_run = mn;

        float lsum = 0.f;
        for (int p = 0; p < chlen; p += 8) {
            const int j = p + jj;
            if (j < chlen) {
                const float pv = __expf(s_ev[wv][j][hh] - mn);
                s_ev[wv][j][hh] = pv;
                lsum += pv;
            }
        }
        lsum += __shfl_xor(lsum, 8);
        lsum += __shfl_xor(lsum, 16);
        lsum += __shfl_xor(lsum, 32);
        d_run = d_run * scl + lsum;

        __asm__ volatile("s_waitcnt lgkmcnt(0)" ::: "memory");

        const float scl4 = __shfl(scl, g4);
        f32x4 t0 = (f32x4)0.f, t1 = (f32x4)0.f, t2 = (f32x4)0.f, t3 = (f32x4)0.f;
        int j = 0;
        for (; j + 4 <= chlen; j += 4) {
            const int s0 = s_src[wv][j],     s1 = s_src[wv][j + 1];
            const int s2 = s_src[wv][j + 2], s3 = s_src[wv][j + 3];
            const float p0 = s_ev[wv][j][g4],     p1 = s_ev[wv][j + 1][g4];
            const float p2 = s_ev[wv][j + 2][g4], p3 = s_ev[wv][j + 3][g4];
            const f32x4 h0 = bf4f(*(const ushort4*)&h_bf[(size_t)s0 * HC + lane * 4]);
            const f32x4 h1 = bf4f(*(const ushort4*)&h_bf[(size_t)s1 * HC + lane * 4]);
            const f32x4 h2 = bf4f(*(const ushort4*)&h_bf[(size_t)s2 * HC + lane * 4]);
            const f32x4 h3 = bf4f(*(const ushort4*)&h_bf[(size_t)s3 * HC + lane * 4]);
#pragma unroll
            for (int q = 0; q < 4; q++) {
                t0[q] += p0 * h0[q];
                t1[q] += p1 * h1[q];
                t2[q] += p2 * h2[q];
                t3[q] += p3 * h3[q];
            }
        }
        for (; j < chlen; j++) {
            const int s0 = s_src[wv][j];
            const float p0 = s_ev[wv][j][g4];
            const f32x4 h0 = bf4f(*(const ushort4*)&h_bf[(size_t)s0 * HC + lane * 4]);
#pragma unroll
            for (int q = 0; q < 4; q++) t0[q] += p0 * h0[q];
        }
#pragma unroll
        for (int q = 0; q < 4; q++)
            acc[q] = acc[q] * scl4 + ((t0[q] + t1[q]) + (t2[q] + t3[q]));
    }

    const float invd = 1.f / (__shfl(d_run, g4) + 1e-16f);
    const f32x4 bv = *(const f32x4*)&bias[lane * 4];
    f32x4 o;
#pragma unroll
    for (int q = 0; q < 4; q++) o[q] = fmaxf(acc[q] * invd + bv[q], 0.f);
    *(f32x4*)&out[(size_t)n * HC + lane * 4] = o;
}

// ---------------------------------------------------------------------------
// Pooling stage 1
// ---------------------------------------------------------------------------
__global__ __launch_bounds__(256) void pool_partial(const float* __restrict__ h,
                                                    const int* __restrict__ batch, int N,
                                                    float* __restrict__ sums) {
    __shared__ int bs[64];
    const int tid = threadIdx.x;
    const int base = blockIdx.x * 64;
    const int cnt = min(64, N - base);
    if (tid < 64 && tid < cnt) bs[tid] = batch[base + tid];
    __syncthreads();

    float acc = 0.f;
    int cur = bs[0];
    for (int i = 0; i < cnt; i++) {
        const int g = bs[i];
        if (g != cur) {
            atomicAdd(&sums[(size_t)cur * HC + tid], acc);
            acc = 0.f;
            cur = g;
        }
        acc += h[(size_t)(base + i) * HC + tid];
    }
    atomicAdd(&sums[(size_t)cur * HC + tid], acc);
}

__global__ __launch_bounds__(256) void pool_div(float* __restrict__ sums,
                                                const int* __restrict__ batch, int N) {
    const int g = blockIdx.x;
    const int tid = threadIdx.x;
    int lo = 0, hi = N;
    while (lo < hi) {
        const int mid = (lo + hi) >> 1;
        if (batch[mid] < g) lo = mid + 1; else hi = mid;
    }
    const int start = lo;
    hi = N;
    while (lo < hi) {
        const int mid = (lo + hi) >> 1;
        if (batch[mid] < g + 1) lo = mid + 1; else hi = mid;
    }
    const float inv = 1.f / fmaxf((float)(lo - start), 1.0f);
    sums[(size_t)g * HC + tid] *= inv;
}

// ---------------------------------------------------------------------------
// MLP head
// ---------------------------------------------------------------------------
__global__ __launch_bounds__(128) void mlp_head(const float* __restrict__ pooled,
                                                const float* __restrict__ w1,
                                                const float* __restrict__ b1,
                                                const float* __restrict__ w2,
                                                const float* __restrict__ b2,
                                                float* __restrict__ out) {
    const int g = blockIdx.x;
    const int tid = threadIdx.x;
    __shared__ float p[HC];
    p[tid] = pooled[g * HC + tid];
    p[tid + 128] = pooled[g * HC + tid + 128];
    __syncthreads();
    float z = b1[tid];
#pragma unroll 8
    for (int k = 0; k < HC; k++) z += p[k] * w1[k * 128 + tid];
    z = fmaxf(z, 0.f);
    float t = z * w2[tid];
#pragma unroll
    for (int m = 32; m >= 1; m >>= 1) t += __shfl_xor(t, m);
    __shared__ float ws2[2];
    if ((tid & 63) == 0) ws2[tid >> 6] = t;
    __syncthreads();
    if (tid == 0) out[g] = ws2[0] + ws2[1] + b2[0];
}

// ---------------------------------------------------------------------------
// Host-side launcher
// ---------------------------------------------------------------------------
extern "C" void kernel_launch(void* const* d_in, const int* in_sizes, int n_in,
                              void* d_out, int out_size, void* d_ws, size_t ws_size,
                              hipStream_t stream) {
    const float* x      = (const float*)d_in[0];
    const int*   ei     = (const int*)d_in[1];
    const int*   batch  = (const int*)d_in[2];
    const float* W1     = (const float*)d_in[3];
    const float* as1    = (const float*)d_in[4];
    const float* ad1    = (const float*)d_in[5];
    const float* b1     = (const float*)d_in[6];
    const float* W2     = (const float*)d_in[7];
    const float* as2    = (const float*)d_in[8];
    const float* ad2    = (const float*)d_in[9];
    const float* b2     = (const float*)d_in[10];
    const float* lin1w  = (const float*)d_in[11];
    const float* lin1b  = (const float*)d_in[12];
    const float* lin2w  = (const float*)d_in[13];
    const float* lin2b  = (const float*)d_in[14];

    const int N   = in_sizes[2];       // 50000
    const int E   = in_sizes[1] / 2;   // 800000
    const int ET  = E + N;
    const int Fin = in_sizes[0] / N;   // 1280
    const int NG  = 64;

    const int nRB = (N + 63) / 64;
    const int nScanBlk = (N + 1023) / 1024;

    const int* src_arr = ei;
    const int* dst_arr = ei + E;

    char* ws = (char*)d_ws;
    size_t off = 0;
    auto alloc = [&](size_t bytes) {
        void* p = ws + off;
        off += (bytes + 255) & ~(size_t)255;
        return p;
    };
    float* h_gemm  = (float*)alloc((size_t)N * HC * sizeof(float));
    float* h_agg   = (float*)alloc((size_t)N * HC * sizeof(float));
    u16*   h_bf    = (u16*)alloc((size_t)N * HC * sizeof(u16));
    float* a_src   = (float*)alloc((size_t)N * NH * sizeof(float));
    float* a_dst   = (float*)alloc((size_t)N * NH * sizeof(float));
    int*   deg     = (int*)alloc((size_t)N * sizeof(int));
    int*   cursor  = (int*)alloc((size_t)N * sizeof(int));
    int*   row_ptr = (int*)alloc((size_t)(N + 1) * sizeof(int));
    int*   partials= (int*)alloc((size_t)1024 * sizeof(int));
    int*   esrc    = (int*)alloc((size_t)ET * sizeof(int));
    float* pooled  = (float*)alloc((size_t)NG * HC * sizeof(float));
    u16* Bh = (u16*)alloc((size_t)Fin * HC * sizeof(u16));
    u16* Bl = (u16*)alloc((size_t)Fin * HC * sizeof(u16));
    (void)ws_size; (void)n_in; (void)out_size;

    // ---- CSR build ----
    hipMemsetAsync(deg, 0, (size_t)N * sizeof(int), stream);
    hipMemsetAsync(cursor, 0, (size_t)N * sizeof(int), stream);
    {
        const int blocks = (ET + 255) / 256;
        count_deg<<<blocks, 256, 0, stream>>>(dst_arr, E, ET, deg);
        scan_block<<<nScanBlk, 256, 0, stream>>>(deg, row_ptr, partials, N);
        scan_partials<<<1, 1024, 0, stream>>>(partials, nScanBlk);
        scan_add<<<(N + 255) / 256, 256, 0, stream>>>(row_ptr, partials, N);
        scatter_edges<<<blocks, 256, 0, stream>>>(src_arr, dst_arr, E, ET, row_ptr,
                                                  cursor, esrc);
    }

    const int aggBlocks = (N + 3) / 4;

    // ---- Layer 1 ----
    pack_b_split<<<(Fin / 32) * 4, 256, 0, stream>>>(W1, Fin, Bh, Bl);
    gemm_fused_split<<<nRB, 256, 0, stream>>>(x, Bh, Bl, h_gemm, N, Fin);
    attn_coef<<<N, 256, 0, stream>>>(h_gemm, as1, ad1, a_src, a_dst, h_bf);
    gat_aggregate_wave<<<aggBlocks, 256, 0, stream>>>(h_bf, a_src, a_dst, row_ptr,
                                                      esrc, b1, h_agg, N);

    // ---- Layer 2 ----
    pack_b_split<<<(HC / 32) * 4, 256, 0, stream>>>(W2, HC, Bh, Bl);
    gemm_fused_split<<<nRB, 256, 0, stream>>>(h_agg, Bh, Bl, h_gemm, N, HC);
    attn_coef<<<N, 256, 0, stream>>>(h_gemm, as2, ad2, a_src, a_dst, h_bf);
    gat_aggregate_wave<<<aggBlocks, 256, 0, stream>>>(h_bf, a_src, a_dst, row_ptr,
                                                      esrc, b2, h_agg, N);

    // ---- Pool + MLP head ----
    hipMemsetAsync(pooled, 0, (size_t)NG * HC * sizeof(float), stream);
    pool_partial<<<(N + 63) / 64, 256, 0, stream>>>(h_agg, batch, N, pooled);
    pool_div<<<NG, 256, 0, stream>>>(pooled, batch, N);
    mlp_head<<<NG, 128, 0, stream>>>(pooled, lin1w, lin1b, lin2w, lin2b, (float*)d_out);
}

// Round 16
// 521.634 us; speedup vs baseline: 1.0153x; 1.0153x over previous
//
#include <hip/hip_runtime.h>
#include <hip/hip_bf16.h>
#include <math.h>

#define HC 256
#define NH 8
#define NEG_SLOPE 0.2f
#define CHW 64   // edges per chunk per wave (aggregation)
#define LDA 136  // LDS row stride in u16 (272 B)
#define MR 32    // rows per block (M-tile)

typedef unsigned short u16;
typedef __attribute__((ext_vector_type(8))) short bf16x8;
typedef __attribute__((ext_vector_type(4))) float f32x4;

__device__ __forceinline__ u16 f2bf(float f) {
    unsigned int u = __float_as_uint(f);
    u += 0x7FFFu + ((u >> 16) & 1u);
    return (u16)(u >> 16);
}
__device__ __forceinline__ float bf2f(u16 s) {
    return __uint_as_float(((unsigned int)s) << 16);
}
__device__ __forceinline__ f32x4 bf4f(ushort4 v) {
    f32x4 r;
    r[0] = bf2f(v.x); r[1] = bf2f(v.y); r[2] = bf2f(v.z); r[3] = bf2f(v.w);
    return r;
}

// raw barrier: own LDS writes drained -> all-wave barrier -> no read hoisting.
#define BAR_LDS()                                                  \
    do {                                                           \
        asm volatile("s_waitcnt lgkmcnt(0)" ::: "memory");         \
        __builtin_amdgcn_s_barrier();                              \
        __builtin_amdgcn_sched_barrier(0);                         \
    } while (0)

// ---------------------------------------------------------------------------
// pack B (fp32 [K x 256]) -> hi/lo, fragment-major
// ---------------------------------------------------------------------------
__global__ __launch_bounds__(256) void pack_b_split(const float* __restrict__ B, int K,
                                                    u16* __restrict__ Bh,
                                                    u16* __restrict__ Bl) {
    const int g = blockIdx.x * 256 + threadIdx.x;
    const int lane = g & 63;
    const int f = (g >> 6) & 15;
    const int kt = g >> 10;
    const int col = f * 16 + (lane & 15);
    const int k0 = kt * 32 + (lane >> 4) * 8;
    bf16x8 hv, lv;
#pragma unroll
    for (int e = 0; e < 8; e++) {
        const float v = B[(size_t)(k0 + e) * HC + col];
        const u16 h = f2bf(v);
        hv[e] = (short)h;
        lv[e] = (short)f2bf(v - bf2f(h));
    }
    const size_t off = (size_t)g * 8;
    *(bf16x8*)(Bh + off) = hv;
    *(bf16x8*)(Bl + off) = lv;
}

// ---------------------------------------------------------------------------
// Fused MFMA GEMM: C = Ah*(Bh + Bl). M-tile = 32 rows -> 2x the blocks of the
// 64-row version (grid-level wave supply: ~16 waves/CU resident vs measured 5).
// 256 threads / 4 waves; wave w owns cols [w*64, w*64+64), rows 0..31
// (2x4 fragments, 16 MFMA per k-tile). Single B register set (lower VGPR).
// A staged in 128-k groups (4 k-tiles), double-buffered, 1 barrier per group,
// per-block group-order rotation kept from round 15. Requires K % 128 == 0.
// ---------------------------------------------------------------------------
__global__ __launch_bounds__(256) void gemm_fused_split(
    const float* __restrict__ A,
    const u16* __restrict__ Bh, const u16* __restrict__ Bl,
    float* __restrict__ C, int M, int K) {
    __shared__ u16 ldsA[2][MR * LDA];   // 2 x 8.7 KB
    const int tid = threadIdx.x;
    const int wid = tid >> 6;        // 0..3
    const int lane = tid & 63;
    const int rowblk = blockIdx.x;
    const int NG4 = K >> 7;          // 128-k groups (10 or 2)
    const int rot = rowblk % NG4;

    f32x4 acc[2][4];
#pragma unroll
    for (int i = 0; i < 2; i++)
#pragma unroll
        for (int j = 0; j < 4; j++) acc[i][j] = (f32x4)0.f;

    // staging map: thread t -> row t>>3 (0..31), 16 consecutive floats at (t&7)*16
    const int srow = tid >> 3;
    const int scc = (tid & 7) * 16;
    const int grow = rowblk * MR + srow;
    const float* aptr = (grow < M) ? (A + (size_t)grow * K + scc) : nullptr;
    const int woff = srow * LDA + scc;

    float4 pf[4];
    auto loadAg = [&](int gg) {
#pragma unroll
        for (int q = 0; q < 4; q++) {
            pf[q] = make_float4(0.f, 0.f, 0.f, 0.f);
            if (aptr) pf[q] = *(const float4*)(aptr + gg * 128 + q * 4);
        }
    };
    auto stageg = [&](int buf) {
#pragma unroll
        for (int p = 0; p < 2; p++) {
            const float vv[8] = {pf[2 * p].x,     pf[2 * p].y,
                                 pf[2 * p].z,     pf[2 * p].w,
                                 pf[2 * p + 1].x, pf[2 * p + 1].y,
                                 pf[2 * p + 1].z, pf[2 * p + 1].w};
            bf16x8 hv;
#pragma unroll
            for (int e = 0; e < 8; e++) hv[e] = (short)f2bf(vv[e]);
            *(bf16x8*)&ldsA[buf][woff + p * 8] = hv;
        }
    };
    auto readA = [&](int buf, int kk, bf16x8* ah) {
#pragma unroll
        for (int i = 0; i < 2; i++)
            ah[i] = *(const bf16x8*)&ldsA[buf][(i * 16 + (lane & 15)) * LDA +
                                              kk * 32 + (lane >> 4) * 8];
    };
    auto loadB = [&](int kt, bf16x8* bh, bf16x8* bl) {
        const u16* bHp = Bh + ((size_t)kt * 16 + wid * 4) * 512 + lane * 8;
        const u16* bLp = Bl + ((size_t)kt * 16 + wid * 4) * 512 + lane * 8;
#pragma unroll
        for (int j = 0; j < 4; j++) {
            bh[j] = *(const bf16x8*)(bHp + j * 512);
            bl[j] = *(const bf16x8*)(bLp + j * 512);
        }
    };
    auto mfma_tile = [&](const bf16x8* ah, const bf16x8* bh, const bf16x8* bl) {
#pragma unroll
        for (int i = 0; i < 2; i++)
#pragma unroll
            for (int j = 0; j < 4; j++) {
                acc[i][j] = __builtin_amdgcn_mfma_f32_16x16x32_bf16(ah[i], bh[j], acc[i][j], 0, 0, 0);
                acc[i][j] = __builtin_amdgcn_mfma_f32_16x16x32_bf16(ah[i], bl[j], acc[i][j], 0, 0, 0);
            }
    };

    // preamble: rotated group 0 staged in buf 0; rotated group 1 in pf (in flight)
    loadAg(rot);
    stageg(0);
    if (NG4 > 1) loadAg((rot + 1) % NG4);
    BAR_LDS();

    bf16x8 bh[4], bl[4];

    int cur = 0;
    for (int g = 0; g < NG4; ++g) {
        const int gg = (g + rot) % NG4;
        if (g + 1 < NG4) stageg(cur ^ 1);
        if (g + 2 < NG4) loadAg((g + 2 + rot) % NG4);

        const int kt0 = gg * 4;
#pragma unroll
        for (int kk = 0; kk < 4; kk++) {
            loadB(kt0 + kk, bh, bl);
            bf16x8 ah[2];
            readA(cur, kk, ah);
            mfma_tile(ah, bh, bl);
        }
        BAR_LDS();
        cur ^= 1;
    }

    // epilogue: C/D layout col = lane&15, row = (lane>>4)*4 + r
    const int r0 = rowblk * MR;
    const int colb = wid * 64 + (lane & 15);
#pragma unroll
    for (int i = 0; i < 2; i++) {
#pragma unroll
        for (int r = 0; r < 4; r++) {
            const int row = r0 + i * 16 + (lane >> 4) * 4 + r;
            if (row < M) {
#pragma unroll
                for (int j = 0; j < 4; j++)
                    C[(size_t)row * HC + colb + j * 16] = acc[i][j][r];
            }
        }
    }
}

// ---------------------------------------------------------------------------
// Per-node attention coefficients + bf16 copy of h for the gather
// ---------------------------------------------------------------------------
__global__ __launch_bounds__(256) void attn_coef(const float* __restrict__ h,
                                                 const float* __restrict__ att_s,
                                                 const float* __restrict__ att_d,
                                                 float* __restrict__ a_src,
                                                 float* __restrict__ a_dst,
                                                 u16* __restrict__ h_bf) {
    const int n = blockIdx.x;
    const int tid = threadIdx.x;
    const float hv = h[(size_t)n * HC + tid];
    h_bf[(size_t)n * HC + tid] = f2bf(hv);
    float p = hv * att_s[tid];
    float q = hv * att_d[tid];
#pragma unroll
    for (int m = 16; m >= 1; m >>= 1) {
        p += __shfl_xor(p, m);
        q += __shfl_xor(q, m);
    }
    if ((tid & 31) == 0) {
        a_src[n * NH + (tid >> 5)] = p;
        a_dst[n * NH + (tid >> 5)] = q;
    }
}

// ---------------------------------------------------------------------------
// CSR build: count, two-level scan, scatter (stores resolved src ids)
// ---------------------------------------------------------------------------
__global__ void count_deg(const int* __restrict__ dst, int E, int ET, int* __restrict__ deg) {
    const int e = blockIdx.x * blockDim.x + threadIdx.x;
    if (e >= ET) return;
    const int d = (e < E) ? dst[e] : (e - E);
    atomicAdd(&deg[d], 1);
}

__global__ __launch_bounds__(256) void scan_block(const int* __restrict__ deg,
                                                  int* __restrict__ row_ptr,
                                                  int* __restrict__ partials, int N) {
    __shared__ int sd[256];
    const int tid = threadIdx.x;
    const int base = blockIdx.x * 1024 + tid * 4;
    int v0 = (base + 0 < N) ? deg[base + 0] : 0;
    int v1 = (base + 1 < N) ? deg[base + 1] : 0;
    int v2 = (base + 2 < N) ? deg[base + 2] : 0;
    int v3 = (base + 3 < N) ? deg[base + 3] : 0;
    const int tsum = v0 + v1 + v2 + v3;
    sd[tid] = tsum;
    __syncthreads();
    int run = tsum;
    for (int off = 1; off < 256; off <<= 1) {
        int t = 0;
        if (tid >= off) t = sd[tid - off];
        __syncthreads();
        run += t;
        sd[tid] = run;
        __syncthreads();
    }
    const int excl = run - tsum;
    int s0 = excl + v0, s1 = s0 + v1, s2 = s1 + v2, s3 = s2 + v3;
    if (base + 0 < N) row_ptr[base + 1] = s0;
    if (base + 1 < N) row_ptr[base + 2] = s1;
    if (base + 2 < N) row_ptr[base + 3] = s2;
    if (base + 3 < N) row_ptr[base + 4] = s3;
    if (tid == 255) partials[blockIdx.x] = run;
}

__global__ __launch_bounds__(1024) void scan_partials(int* __restrict__ partials, int nb) {
    __shared__ int sd[1024];
    const int tid = threadIdx.x;
    int v = (tid < nb) ? partials[tid] : 0;
    sd[tid] = v;
    __syncthreads();
    int run = v;
    for (int off = 1; off < 1024; off <<= 1) {
        int t = 0;
        if (tid >= off) t = sd[tid - off];
        __syncthreads();
        run += t;
        sd[tid] = run;
        __syncthreads();
    }
    if (tid < nb) partials[tid] = run - v;  // exclusive
}

__global__ __launch_bounds__(256) void scan_add(int* __restrict__ row_ptr,
                                                const int* __restrict__ partials, int N) {
    const int i = blockIdx.x * 256 + threadIdx.x;
    if (i == 0) row_ptr[0] = 0;
    if (i < N) row_ptr[i + 1] += partials[i >> 10];
}

__global__ void scatter_edges(const int* __restrict__ src_in, const int* __restrict__ dst,
                              int E, int ET, const int* __restrict__ row_ptr,
                              int* __restrict__ cursor, int* __restrict__ esrc) {
    const int e = blockIdx.x * blockDim.x + threadIdx.x;
    if (e >= ET) return;
    const int d = (e < E) ? dst[e] : (e - E);
    const int s = (e < E) ? src_in[e] : (e - E);
    const int pos = atomicAdd(&cursor[d], 1);
    esrc[row_ptr[d] + pos] = s;
}

// ---------------------------------------------------------------------------
// GAT aggregation, one WAVE per dst node. Gather reads bf16 h rows (512B/row).
// ---------------------------------------------------------------------------
__global__ __launch_bounds__(256) void gat_aggregate_wave(
    const u16* __restrict__ h_bf, const float* __restrict__ a_src,
    const float* __restrict__ a_dst, const int* __restrict__ row_ptr,
    const int* __restrict__ esrc, const float* __restrict__ bias,
    float* __restrict__ out, int N) {
    __shared__ int   s_src[4][CHW];
    __shared__ float s_ev[4][CHW][NH];

    const int tid = threadIdx.x;
    const int wv = tid >> 6;
    const int lane = tid & 63;
    const int n = blockIdx.x * 4 + wv;
    if (n >= N) return;

    const int beg = row_ptr[n];
    const int deg = row_ptr[n + 1] - beg;
    const int jj = lane >> 3;   // edge slot 0..7
    const int hh = lane & 7;    // head for softmax lanes
    const int g4 = lane >> 3;   // head for gather features

    const float adh = a_dst[n * NH + hh];
    float m_run = -1e30f, d_run = 0.f;
    f32x4 acc = (f32x4)0.f;

    for (int c0 = 0; c0 < deg; c0 += CHW) {
        const int chlen = min(CHW, deg - c0);

        float lmax = -1e30f;
        for (int p = 0; p < chlen; p += 8) {
            const int j = p + jj;
            if (j < chlen) {
                const int s = esrc[beg + c0 + j];
                if (hh == 0) s_src[wv][j] = s;
                float v = a_src[s * NH + hh] + adh;
                v = (v > 0.f) ? v : NEG_SLOPE * v;
                s_ev[wv][j][hh] = v;
                lmax = fmaxf(lmax, v);
            }
        }
        lmax = fmaxf(lmax, __shfl_xor(lmax, 8));
        lmax = fmaxf(lmax, __shfl_xor(lmax, 16));
        lmax = fmaxf(lmax, __shfl_xor(lmax, 32));
        const float mo = m_run;
        const float mn = fmaxf(mo, lmax);
        const float scl = __expf(mo - mn);
        m_run = mn;

        float lsum = 0.f;
        for (int p = 0; p < chlen; p += 8) {
            const int j = p + jj;
            if (j < chlen) {
                const float pv = __expf(s_ev[wv][j][hh] - mn);
                s_ev[wv][j][hh] = pv;
                lsum += pv;
            }
        }
        lsum += __shfl_xor(lsum, 8);
        lsum += __shfl_xor(lsum, 16);
        lsum += __shfl_xor(lsum, 32);
        d_run = d_run * scl + lsum;

        __asm__ volatile("s_waitcnt lgkmcnt(0)" ::: "memory");

        const float scl4 = __shfl(scl, g4);
        f32x4 t0 = (f32x4)0.f, t1 = (f32x4)0.f, t2 = (f32x4)0.f, t3 = (f32x4)0.f;
        int j = 0;
        for (; j + 4 <= chlen; j += 4) {
            const int s0 = s_src[wv][j],     s1 = s_src[wv][j + 1];
            const int s2 = s_src[wv][j + 2], s3 = s_src[wv][j + 3];
            const float p0 = s_ev[wv][j][g4],     p1 = s_ev[wv][j + 1][g4];
            const float p2 = s_ev[wv][j + 2][g4], p3 = s_ev[wv][j + 3][g4];
            const f32x4 h0 = bf4f(*(const ushort4*)&h_bf[(size_t)s0 * HC + lane * 4]);
            const f32x4 h1 = bf4f(*(const ushort4*)&h_bf[(size_t)s1 * HC + lane * 4]);
            const f32x4 h2 = bf4f(*(const ushort4*)&h_bf[(size_t)s2 * HC + lane * 4]);
            const f32x4 h3 = bf4f(*(const ushort4*)&h_bf[(size_t)s3 * HC + lane * 4]);
#pragma unroll
            for (int q = 0; q < 4; q++) {
                t0[q] += p0 * h0[q];
                t1[q] += p1 * h1[q];
                t2[q] += p2 * h2[q];
                t3[q] += p3 * h3[q];
            }
        }
        for (; j < chlen; j++) {
            const int s0 = s_src[wv][j];
            const float p0 = s_ev[wv][j][g4];
            const f32x4 h0 = bf4f(*(const ushort4*)&h_bf[(size_t)s0 * HC + lane * 4]);
#pragma unroll
            for (int q = 0; q < 4; q++) t0[q] += p0 * h0[q];
        }
#pragma unroll
        for (int q = 0; q < 4; q++)
            acc[q] = acc[q] * scl4 + ((t0[q] + t1[q]) + (t2[q] + t3[q]));
    }

    const float invd = 1.f / (__shfl(d_run, g4) + 1e-16f);
    const f32x4 bv = *(const f32x4*)&bias[lane * 4];
    f32x4 o;
#pragma unroll
    for (int q = 0; q < 4; q++) o[q] = fmaxf(acc[q] * invd + bv[q], 0.f);
    *(f32x4*)&out[(size_t)n * HC + lane * 4] = o;
}

// ---------------------------------------------------------------------------
// Pooling stage 1
// ---------------------------------------------------------------------------
__global__ __launch_bounds__(256) void pool_partial(const float* __restrict__ h,
                                                    const int* __restrict__ batch, int N,
                                                    float* __restrict__ sums) {
    __shared__ int bs[64];
    const int tid = threadIdx.x;
    const int base = blockIdx.x * 64;
    const int cnt = min(64, N - base);
    if (tid < 64 && tid < cnt) bs[tid] = batch[base + tid];
    __syncthreads();

    float acc = 0.f;
    int cur = bs[0];
    for (int i = 0; i < cnt; i++) {
        const int g = bs[i];
        if (g != cur) {
            atomicAdd(&sums[(size_t)cur * HC + tid], acc);
            acc = 0.f;
            cur = g;
        }
        acc += h[(size_t)(base + i) * HC + tid];
    }
    atomicAdd(&sums[(size_t)cur * HC + tid], acc);
}

__global__ __launch_bounds__(256) void pool_div(float* __restrict__ sums,
                                                const int* __restrict__ batch, int N) {
    const int g = blockIdx.x;
    const int tid = threadIdx.x;
    int lo = 0, hi = N;
    while (lo < hi) {
        const int mid = (lo + hi) >> 1;
        if (batch[mid] < g) lo = mid + 1; else hi = mid;
    }
    const int start = lo;
    hi = N;
    while (lo < hi) {
        const int mid = (lo + hi) >> 1;
        if (batch[mid] < g + 1) lo = mid + 1; else hi = mid;
    }
    const float inv = 1.f / fmaxf((float)(lo - start), 1.0f);
    sums[(size_t)g * HC + tid] *= inv;
}

// ---------------------------------------------------------------------------
// MLP head
// ---------------------------------------------------------------------------
__global__ __launch_bounds__(128) void mlp_head(const float* __restrict__ pooled,
                                                const float* __restrict__ w1,
                                                const float* __restrict__ b1,
                                                const float* __restrict__ w2,
                                                const float* __restrict__ b2,
                                                float* __restrict__ out) {
    const int g = blockIdx.x;
    const int tid = threadIdx.x;
    __shared__ float p[HC];
    p[tid] = pooled[g * HC + tid];
    p[tid + 128] = pooled[g * HC + tid + 128];
    __syncthreads();
    float z = b1[tid];
#pragma unroll 8
    for (int k = 0; k < HC; k++) z += p[k] * w1[k * 128 + tid];
    z = fmaxf(z, 0.f);
    float t = z * w2[tid];
#pragma unroll
    for (int m = 32; m >= 1; m >>= 1) t += __shfl_xor(t, m);
    __shared__ float ws2[2];
    if ((tid & 63) == 0) ws2[tid >> 6] = t;
    __syncthreads();
    if (tid == 0) out[g] = ws2[0] + ws2[1] + b2[0];
}

// ---------------------------------------------------------------------------
// Host-side launcher
// ---------------------------------------------------------------------------
extern "C" void kernel_launch(void* const* d_in, const int* in_sizes, int n_in,
                              void* d_out, int out_size, void* d_ws, size_t ws_size,
                              hipStream_t stream) {
    const float* x      = (const float*)d_in[0];
    const int*   ei     = (const int*)d_in[1];
    const int*   batch  = (const int*)d_in[2];
    const float* W1     = (const float*)d_in[3];
    const float* as1    = (const float*)d_in[4];
    const float* ad1    = (const float*)d_in[5];
    const float* b1     = (const float*)d_in[6];
    const float* W2     = (const float*)d_in[7];
    const float* as2    = (const float*)d_in[8];
    const float* ad2    = (const float*)d_in[9];
    const float* b2     = (const float*)d_in[10];
    const float* lin1w  = (const float*)d_in[11];
    const float* lin1b  = (const float*)d_in[12];
    const float* lin2w  = (const float*)d_in[13];
    const float* lin2b  = (const float*)d_in[14];

    const int N   = in_sizes[2];       // 50000
    const int E   = in_sizes[1] / 2;   // 800000
    const int ET  = E + N;
    const int Fin = in_sizes[0] / N;   // 1280
    const int NG  = 64;

    const int nRB = (N + MR - 1) / MR;   // 1563 blocks of 32 rows
    const int nScanBlk = (N + 1023) / 1024;

    const int* src_arr = ei;
    const int* dst_arr = ei + E;

    char* ws = (char*)d_ws;
    size_t off = 0;
    auto alloc = [&](size_t bytes) {
        void* p = ws + off;
        off += (bytes + 255) & ~(size_t)255;
        return p;
    };
    float* h_gemm  = (float*)alloc((size_t)N * HC * sizeof(float));
    float* h_agg   = (float*)alloc((size_t)N * HC * sizeof(float));
    u16*   h_bf    = (u16*)alloc((size_t)N * HC * sizeof(u16));
    float* a_src   = (float*)alloc((size_t)N * NH * sizeof(float));
    float* a_dst   = (float*)alloc((size_t)N * NH * sizeof(float));
    int*   deg     = (int*)alloc((size_t)N * sizeof(int));
    int*   cursor  = (int*)alloc((size_t)N * sizeof(int));
    int*   row_ptr = (int*)alloc((size_t)(N + 1) * sizeof(int));
    int*   partials= (int*)alloc((size_t)1024 * sizeof(int));
    int*   esrc    = (int*)alloc((size_t)ET * sizeof(int));
    float* pooled  = (float*)alloc((size_t)NG * HC * sizeof(float));
    u16* Bh = (u16*)alloc((size_t)Fin * HC * sizeof(u16));
    u16* Bl = (u16*)alloc((size_t)Fin * HC * sizeof(u16));
    (void)ws_size; (void)n_in; (void)out_size;

    // ---- CSR build ----
    hipMemsetAsync(deg, 0, (size_t)N * sizeof(int), stream);
    hipMemsetAsync(cursor, 0, (size_t)N * sizeof(int), stream);
    {
        const int blocks = (ET + 255) / 256;
        count_deg<<<blocks, 256, 0, stream>>>(dst_arr, E, ET, deg);
        scan_block<<<nScanBlk, 256, 0, stream>>>(deg, row_ptr, partials, N);
        scan_partials<<<1, 1024, 0, stream>>>(partials, nScanBlk);
        scan_add<<<(N + 255) / 256, 256, 0, stream>>>(row_ptr, partials, N);
        scatter_edges<<<blocks, 256, 0, stream>>>(src_arr, dst_arr, E, ET, row_ptr,
                                                  cursor, esrc);
    }

    const int aggBlocks = (N + 3) / 4;

    // ---- Layer 1 ----
    pack_b_split<<<(Fin / 32) * 4, 256, 0, stream>>>(W1, Fin, Bh, Bl);
    gemm_fused_split<<<nRB, 256, 0, stream>>>(x, Bh, Bl, h_gemm, N, Fin);
    attn_coef<<<N, 256, 0, stream>>>(h_gemm, as1, ad1, a_src, a_dst, h_bf);
    gat_aggregate_wave<<<aggBlocks, 256, 0, stream>>>(h_bf, a_src, a_dst, row_ptr,
                                                      esrc, b1, h_agg, N);

    // ---- Layer 2 ----
    pack_b_split<<<(HC / 32) * 4, 256, 0, stream>>>(W2, HC, Bh, Bl);
    gemm_fused_split<<<nRB, 256, 0, stream>>>(h_agg, Bh, Bl, h_gemm, N, HC);
    attn_coef<<<N, 256, 0, stream>>>(h_gemm, as2, ad2, a_src, a_dst, h_bf);
    gat_aggregate_wave<<<aggBlocks, 256, 0, stream>>>(h_bf, a_src, a_dst, row_ptr,
                                                      esrc, b2, h_agg, N);

    // ---- Pool + MLP head ----
    hipMemsetAsync(pooled, 0, (size_t)NG * HC * sizeof(float), stream);
    pool_partial<<<(N + 63) / 64, 256, 0, stream>>>(h_agg, batch, N, pooled);
    pool_div<<<NG, 256, 0, stream>>>(pooled, batch, N);
    mlp_head<<<NG, 128, 0, stream>>>(pooled, lin1w, lin1b, lin2w, lin2b, (float*)d_out);
}

// Round 17
// 468.477 us; speedup vs baseline: 1.1305x; 1.1135x over previous
//
#include <hip/hip_runtime.h>
#include <hip/hip_bf16.h>
#include <math.h>

#define HC 256
#define NH 8
#define NEG_SLOPE 0.2f
#define CHW 64   // edges per chunk per wave (aggregation)
#define LDA 136  // LDS row stride in u16 (272 B)
#define MR 32    // rows per block (M-tile)

typedef unsigned short u16;
typedef __attribute__((ext_vector_type(8))) short bf16x8;
typedef __attribute__((ext_vector_type(4))) float f32x4;

__device__ __forceinline__ u16 f2bf(float f) {
    unsigned int u = __float_as_uint(f);
    u += 0x7FFFu + ((u >> 16) & 1u);
    return (u16)(u >> 16);
}
__device__ __forceinline__ float bf2f(u16 s) {
    return __uint_as_float(((unsigned int)s) << 16);
}
__device__ __forceinline__ f32x4 bf4f(ushort4 v) {
    f32x4 r;
    r[0] = bf2f(v.x); r[1] = bf2f(v.y); r[2] = bf2f(v.z); r[3] = bf2f(v.w);
    return r;
}

// raw barrier: own LDS writes drained -> all-wave barrier -> no read hoisting.
#define BAR_LDS()                                                  \
    do {                                                           \
        asm volatile("s_waitcnt lgkmcnt(0)" ::: "memory");         \
        __builtin_amdgcn_s_barrier();                              \
        __builtin_amdgcn_sched_barrier(0);                         \
    } while (0)

// ---------------------------------------------------------------------------
// pack B (fp32 [K x 256]) -> hi/lo, fragment-major
// ---------------------------------------------------------------------------
__global__ __launch_bounds__(256) void pack_b_split(const float* __restrict__ B, int K,
                                                    u16* __restrict__ Bh,
                                                    u16* __restrict__ Bl) {
    const int g = blockIdx.x * 256 + threadIdx.x;
    const int lane = g & 63;
    const int f = (g >> 6) & 15;
    const int kt = g >> 10;
    const int col = f * 16 + (lane & 15);
    const int k0 = kt * 32 + (lane >> 4) * 8;
    bf16x8 hv, lv;
#pragma unroll
    for (int e = 0; e < 8; e++) {
        const float v = B[(size_t)(k0 + e) * HC + col];
        const u16 h = f2bf(v);
        hv[e] = (short)h;
        lv[e] = (short)f2bf(v - bf2f(h));
    }
    const size_t off = (size_t)g * 8;
    *(bf16x8*)(Bh + off) = hv;
    *(bf16x8*)(Bl + off) = lv;
}

// ---------------------------------------------------------------------------
// Fused MFMA GEMM + attention epilogue.
// C = Ah*(Bh + Bl); A is fp32 (layer 1, converted once) or bf16 (layer 2,
// direct copy), selected by template. Epilogue writes h as bf16 AND computes
// a_src/a_dst per row in-register: wave w's 64 cols = heads 2w,2w+1 exactly,
// reduced with 4 shfl_xor steps over the 16-lane row group. No attn_coef pass.
// Tile 32x256, 4 waves; A staged in 128-k groups, dbuf, 1 barrier per group.
// Requires K % 128 == 0 (K = 1280 or 256).
// ---------------------------------------------------------------------------
template <typename AT>
__global__ __launch_bounds__(256) void gemm_fused(
    const AT* __restrict__ A,
    const u16* __restrict__ Bh, const u16* __restrict__ Bl,
    const float* __restrict__ att_s, const float* __restrict__ att_d,
    u16* __restrict__ h_out, float* __restrict__ a_src, float* __restrict__ a_dst,
    int M, int K) {
    __shared__ u16 ldsA[2][MR * LDA];   // 2 x 8.7 KB
    const int tid = threadIdx.x;
    const int wid = tid >> 6;        // 0..3
    const int lane = tid & 63;
    const int rowblk = blockIdx.x;
    const int NG4 = K >> 7;          // 128-k groups (10 or 2)
    const int rot = rowblk % NG4;

    f32x4 acc[2][4];
#pragma unroll
    for (int i = 0; i < 2; i++)
#pragma unroll
        for (int j = 0; j < 4; j++) acc[i][j] = (f32x4)0.f;

    // staging map: thread t -> row t>>3 (0..31), 16 elems at (t&7)*16 per group
    const int srow = tid >> 3;
    const int scc = (tid & 7) * 16;
    const int grow = rowblk * MR + srow;
    const AT* aptr = (grow < M) ? (A + (size_t)grow * K + scc) : nullptr;
    const int woff = srow * LDA + scc;

    float4 pf[4];   // fp32 path prefetch
    uint4 pu[2];    // bf16 path prefetch
    auto loadAg = [&](int gg) {
        if constexpr (sizeof(AT) == 4) {
#pragma unroll
            for (int q = 0; q < 4; q++) {
                pf[q] = make_float4(0.f, 0.f, 0.f, 0.f);
                if (aptr) pf[q] = *(const float4*)((const float*)aptr + gg * 128 + q * 4);
            }
        } else {
            pu[0] = make_uint4(0, 0, 0, 0);
            pu[1] = make_uint4(0, 0, 0, 0);
            if (aptr) {
                pu[0] = *(const uint4*)((const u16*)aptr + gg * 128);
                pu[1] = *(const uint4*)((const u16*)aptr + gg * 128 + 8);
            }
        }
    };
    auto stageg = [&](int buf) {
        if constexpr (sizeof(AT) == 4) {
#pragma unroll
            for (int p = 0; p < 2; p++) {
                const float vv[8] = {pf[2 * p].x,     pf[2 * p].y,
                                     pf[2 * p].z,     pf[2 * p].w,
                                     pf[2 * p + 1].x, pf[2 * p + 1].y,
                                     pf[2 * p + 1].z, pf[2 * p + 1].w};
                bf16x8 hv;
#pragma unroll
                for (int e = 0; e < 8; e++) hv[e] = (short)f2bf(vv[e]);
                *(bf16x8*)&ldsA[buf][woff + p * 8] = hv;
            }
        } else {
            *(uint4*)&ldsA[buf][woff] = pu[0];
            *(uint4*)&ldsA[buf][woff + 8] = pu[1];
        }
    };
    auto readA = [&](int buf, int kk, bf16x8* ah) {
#pragma unroll
        for (int i = 0; i < 2; i++)
            ah[i] = *(const bf16x8*)&ldsA[buf][(i * 16 + (lane & 15)) * LDA +
                                              kk * 32 + (lane >> 4) * 8];
    };
    auto loadB = [&](int kt, bf16x8* bh, bf16x8* bl) {
        const u16* bHp = Bh + ((size_t)kt * 16 + wid * 4) * 512 + lane * 8;
        const u16* bLp = Bl + ((size_t)kt * 16 + wid * 4) * 512 + lane * 8;
#pragma unroll
        for (int j = 0; j < 4; j++) {
            bh[j] = *(const bf16x8*)(bHp + j * 512);
            bl[j] = *(const bf16x8*)(bLp + j * 512);
        }
    };
    auto mfma_tile = [&](const bf16x8* ah, const bf16x8* bh, const bf16x8* bl) {
#pragma unroll
        for (int i = 0; i < 2; i++)
#pragma unroll
            for (int j = 0; j < 4; j++) {
                acc[i][j] = __builtin_amdgcn_mfma_f32_16x16x32_bf16(ah[i], bh[j], acc[i][j], 0, 0, 0);
                acc[i][j] = __builtin_amdgcn_mfma_f32_16x16x32_bf16(ah[i], bl[j], acc[i][j], 0, 0, 0);
            }
    };

    // preamble: rotated group 0 staged in buf 0; rotated group 1 in flight
    loadAg(rot);
    stageg(0);
    if (NG4 > 1) loadAg((rot + 1) % NG4);
    BAR_LDS();

    bf16x8 bh[4], bl[4];
    int cur = 0;
    for (int g = 0; g < NG4; ++g) {
        const int gg = (g + rot) % NG4;
        if (g + 1 < NG4) stageg(cur ^ 1);
        if (g + 2 < NG4) loadAg((g + 2 + rot) % NG4);

        const int kt0 = gg * 4;
#pragma unroll
        for (int kk = 0; kk < 4; kk++) {
            loadB(kt0 + kk, bh, bl);
            bf16x8 ah[2];
            readA(cur, kk, ah);
            mfma_tile(ah, bh, bl);
        }
        BAR_LDS();
        cur ^= 1;
    }

    // ---- epilogue: h (bf16) + per-head attention dots ----
    // C/D layout: row = i*16 + (lane>>4)*4 + r, col = wid*64 + (lane&15) + j*16.
    // Within this wave, cols j=0,1 belong to head 2*wid; j=2,3 to head 2*wid+1.
    const int r0 = rowblk * MR;
    const int colb = wid * 64 + (lane & 15);
    float asw[4], adw[4];
#pragma unroll
    for (int j = 0; j < 4; j++) {
        asw[j] = att_s[colb + j * 16];
        adw[j] = att_d[colb + j * 16];
    }
#pragma unroll
    for (int i = 0; i < 2; i++) {
#pragma unroll
        for (int r = 0; r < 4; r++) {
            const int row = r0 + i * 16 + (lane >> 4) * 4 + r;
            float ps0 = acc[i][0][r] * asw[0] + acc[i][1][r] * asw[1];
            float ps1 = acc[i][2][r] * asw[2] + acc[i][3][r] * asw[3];
            float pd0 = acc[i][0][r] * adw[0] + acc[i][1][r] * adw[1];
            float pd1 = acc[i][2][r] * adw[2] + acc[i][3][r] * adw[3];
#pragma unroll
            for (int m = 1; m <= 8; m <<= 1) {
                ps0 += __shfl_xor(ps0, m);
                ps1 += __shfl_xor(ps1, m);
                pd0 += __shfl_xor(pd0, m);
                pd1 += __shfl_xor(pd1, m);
            }
            if (row < M) {
#pragma unroll
                for (int j = 0; j < 4; j++)
                    h_out[(size_t)row * HC + colb + j * 16] = f2bf(acc[i][j][r]);
                if ((lane & 15) == 0) {
                    a_src[row * NH + 2 * wid + 0] = ps0;
                    a_src[row * NH + 2 * wid + 1] = ps1;
                    a_dst[row * NH + 2 * wid + 0] = pd0;
                    a_dst[row * NH + 2 * wid + 1] = pd1;
                }
            }
        }
    }
}

// ---------------------------------------------------------------------------
// CSR build: count, two-level scan, scatter (stores resolved src ids)
// ---------------------------------------------------------------------------
__global__ void count_deg(const int* __restrict__ dst, int E, int ET, int* __restrict__ deg) {
    const int e = blockIdx.x * blockDim.x + threadIdx.x;
    if (e >= ET) return;
    const int d = (e < E) ? dst[e] : (e - E);
    atomicAdd(&deg[d], 1);
}

__global__ __launch_bounds__(256) void scan_block(const int* __restrict__ deg,
                                                  int* __restrict__ row_ptr,
                                                  int* __restrict__ partials, int N) {
    __shared__ int sd[256];
    const int tid = threadIdx.x;
    const int base = blockIdx.x * 1024 + tid * 4;
    int v0 = (base + 0 < N) ? deg[base + 0] : 0;
    int v1 = (base + 1 < N) ? deg[base + 1] : 0;
    int v2 = (base + 2 < N) ? deg[base + 2] : 0;
    int v3 = (base + 3 < N) ? deg[base + 3] : 0;
    const int tsum = v0 + v1 + v2 + v3;
    sd[tid] = tsum;
    __syncthreads();
    int run = tsum;
    for (int off = 1; off < 256; off <<= 1) {
        int t = 0;
        if (tid >= off) t = sd[tid - off];
        __syncthreads();
        run += t;
        sd[tid] = run;
        __syncthreads();
    }
    const int excl = run - tsum;
    int s0 = excl + v0, s1 = s0 + v1, s2 = s1 + v2, s3 = s2 + v3;
    if (base + 0 < N) row_ptr[base + 1] = s0;
    if (base + 1 < N) row_ptr[base + 2] = s1;
    if (base + 2 < N) row_ptr[base + 3] = s2;
    if (base + 3 < N) row_ptr[base + 4] = s3;
    if (tid == 255) partials[blockIdx.x] = run;
}

__global__ __launch_bounds__(1024) void scan_partials(int* __restrict__ partials, int nb) {
    __shared__ int sd[1024];
    const int tid = threadIdx.x;
    int v = (tid < nb) ? partials[tid] : 0;
    sd[tid] = v;
    __syncthreads();
    int run = v;
    for (int off = 1; off < 1024; off <<= 1) {
        int t = 0;
        if (tid >= off) t = sd[tid - off];
        __syncthreads();
        run += t;
        sd[tid] = run;
        __syncthreads();
    }
    if (tid < nb) partials[tid] = run - v;  // exclusive
}

__global__ __launch_bounds__(256) void scan_add(int* __restrict__ row_ptr,
                                                const int* __restrict__ partials, int N) {
    const int i = blockIdx.x * 256 + threadIdx.x;
    if (i == 0) row_ptr[0] = 0;
    if (i < N) row_ptr[i + 1] += partials[i >> 10];
}

__global__ void scatter_edges(const int* __restrict__ src_in, const int* __restrict__ dst,
                              int E, int ET, const int* __restrict__ row_ptr,
                              int* __restrict__ cursor, int* __restrict__ esrc) {
    const int e = blockIdx.x * blockDim.x + threadIdx.x;
    if (e >= ET) return;
    const int d = (e < E) ? dst[e] : (e - E);
    const int s = (e < E) ? src_in[e] : (e - E);
    const int pos = atomicAdd(&cursor[d], 1);
    esrc[row_ptr[d] + pos] = s;
}

// ---------------------------------------------------------------------------
// GAT aggregation, one WAVE per dst node. Gather reads bf16 h rows (512B/row).
// OUT type templated: u16 (bf16, feeds next GEMM) or float (feeds pooling).
// ---------------------------------------------------------------------------
template <typename OT>
__global__ __launch_bounds__(256) void gat_aggregate_wave(
    const u16* __restrict__ h_bf, const float* __restrict__ a_src,
    const float* __restrict__ a_dst, const int* __restrict__ row_ptr,
    const int* __restrict__ esrc, const float* __restrict__ bias,
    OT* __restrict__ out, int N) {
    __shared__ int   s_src[4][CHW];
    __shared__ float s_ev[4][CHW][NH];

    const int tid = threadIdx.x;
    const int wv = tid >> 6;
    const int lane = tid & 63;
    const int n = blockIdx.x * 4 + wv;
    if (n >= N) return;

    const int beg = row_ptr[n];
    const int deg = row_ptr[n + 1] - beg;
    const int jj = lane >> 3;   // edge slot 0..7
    const int hh = lane & 7;    // head for softmax lanes
    const int g4 = lane >> 3;   // head for gather features

    const float adh = a_dst[n * NH + hh];
    float m_run = -1e30f, d_run = 0.f;
    f32x4 acc = (f32x4)0.f;

    for (int c0 = 0; c0 < deg; c0 += CHW) {
        const int chlen = min(CHW, deg - c0);

        float lmax = -1e30f;
        for (int p = 0; p < chlen; p += 8) {
            const int j = p + jj;
            if (j < chlen) {
                const int s = esrc[beg + c0 + j];
                if (hh == 0) s_src[wv][j] = s;
                float v = a_src[s * NH + hh] + adh;
                v = (v > 0.f) ? v : NEG_SLOPE * v;
                s_ev[wv][j][hh] = v;
                lmax = fmaxf(lmax, v);
            }
        }
        lmax = fmaxf(lmax, __shfl_xor(lmax, 8));
        lmax = fmaxf(lmax, __shfl_xor(lmax, 16));
        lmax = fmaxf(lmax, __shfl_xor(lmax, 32));
        const float mo = m_run;
        const float mn = fmaxf(mo, lmax);
        const float scl = __expf(mo - mn);
        m_run = mn;

        float lsum = 0.f;
        for (int p = 0; p < chlen; p += 8) {
            const int j = p + jj;
            if (j < chlen) {
                const float pv = __expf(s_ev[wv][j][hh] - mn);
                s_ev[wv][j][hh] = pv;
                lsum += pv;
            }
        }
        lsum += __shfl_xor(lsum, 8);
        lsum += __shfl_xor(lsum, 16);
        lsum += __shfl_xor(lsum, 32);
        d_run = d_run * scl + lsum;

        __asm__ volatile("s_waitcnt lgkmcnt(0)" ::: "memory");

        const float scl4 = __shfl(scl, g4);
        f32x4 t0 = (f32x4)0.f, t1 = (f32x4)0.f, t2 = (f32x4)0.f, t3 = (f32x4)0.f;
        int j = 0;
        for (; j + 4 <= chlen; j += 4) {
            const int s0 = s_src[wv][j],     s1 = s_src[wv][j + 1];
            const int s2 = s_src[wv][j + 2], s3 = s_src[wv][j + 3];
            const float p0 = s_ev[wv][j][g4],     p1 = s_ev[wv][j + 1][g4];
            const float p2 = s_ev[wv][j + 2][g4], p3 = s_ev[wv][j + 3][g4];
            const f32x4 h0 = bf4f(*(const ushort4*)&h_bf[(size_t)s0 * HC + lane * 4]);
            const f32x4 h1 = bf4f(*(const ushort4*)&h_bf[(size_t)s1 * HC + lane * 4]);
            const f32x4 h2 = bf4f(*(const ushort4*)&h_bf[(size_t)s2 * HC + lane * 4]);
            const f32x4 h3 = bf4f(*(const ushort4*)&h_bf[(size_t)s3 * HC + lane * 4]);
#pragma unroll
            for (int q = 0; q < 4; q++) {
                t0[q] += p0 * h0[q];
                t1[q] += p1 * h1[q];
                t2[q] += p2 * h2[q];
                t3[q] += p3 * h3[q];
            }
        }
        for (; j < chlen; j++) {
            const int s0 = s_src[wv][j];
            const float p0 = s_ev[wv][j][g4];
            const f32x4 h0 = bf4f(*(const ushort4*)&h_bf[(size_t)s0 * HC + lane * 4]);
#pragma unroll
            for (int q = 0; q < 4; q++) t0[q] += p0 * h0[q];
        }
#pragma unroll
        for (int q = 0; q < 4; q++)
            acc[q] = acc[q] * scl4 + ((t0[q] + t1[q]) + (t2[q] + t3[q]));
    }

    const float invd = 1.f / (__shfl(d_run, g4) + 1e-16f);
    const f32x4 bv = *(const f32x4*)&bias[lane * 4];
    if constexpr (sizeof(OT) == 2) {
        ushort4 o4;
        o4.x = f2bf(fmaxf(acc[0] * invd + bv[0], 0.f));
        o4.y = f2bf(fmaxf(acc[1] * invd + bv[1], 0.f));
        o4.z = f2bf(fmaxf(acc[2] * invd + bv[2], 0.f));
        o4.w = f2bf(fmaxf(acc[3] * invd + bv[3], 0.f));
        *(ushort4*)&out[(size_t)n * HC + lane * 4] = o4;
    } else {
        f32x4 o;
#pragma unroll
        for (int q = 0; q < 4; q++) o[q] = fmaxf(acc[q] * invd + bv[q], 0.f);
        *(f32x4*)&out[(size_t)n * HC + lane * 4] = o;
    }
}

// ---------------------------------------------------------------------------
// Pooling stage 1
// ---------------------------------------------------------------------------
__global__ __launch_bounds__(256) void pool_partial(const float* __restrict__ h,
                                                    const int* __restrict__ batch, int N,
                                                    float* __restrict__ sums) {
    __shared__ int bs[64];
    const int tid = threadIdx.x;
    const int base = blockIdx.x * 64;
    const int cnt = min(64, N - base);
    if (tid < 64 && tid < cnt) bs[tid] = batch[base + tid];
    __syncthreads();

    float acc = 0.f;
    int cur = bs[0];
    for (int i = 0; i < cnt; i++) {
        const int g = bs[i];
        if (g != cur) {
            atomicAdd(&sums[(size_t)cur * HC + tid], acc);
            acc = 0.f;
            cur = g;
        }
        acc += h[(size_t)(base + i) * HC + tid];
    }
    atomicAdd(&sums[(size_t)cur * HC + tid], acc);
}

__global__ __launch_bounds__(256) void pool_div(float* __restrict__ sums,
                                                const int* __restrict__ batch, int N) {
    const int g = blockIdx.x;
    const int tid = threadIdx.x;
    int lo = 0, hi = N;
    while (lo < hi) {
        const int mid = (lo + hi) >> 1;
        if (batch[mid] < g) lo = mid + 1; else hi = mid;
    }
    const int start = lo;
    hi = N;
    while (lo < hi) {
        const int mid = (lo + hi) >> 1;
        if (batch[mid] < g + 1) lo = mid + 1; else hi = mid;
    }
    const float inv = 1.f / fmaxf((float)(lo - start), 1.0f);
    sums[(size_t)g * HC + tid] *= inv;
}

// ---------------------------------------------------------------------------
// MLP head
// ---------------------------------------------------------------------------
__global__ __launch_bounds__(128) void mlp_head(const float* __restrict__ pooled,
                                                const float* __restrict__ w1,
                                                const float* __restrict__ b1,
                                                const float* __restrict__ w2,
                                                const float* __restrict__ b2,
                                                float* __restrict__ out) {
    const int g = blockIdx.x;
    const int tid = threadIdx.x;
    __shared__ float p[HC];
    p[tid] = pooled[g * HC + tid];
    p[tid + 128] = pooled[g * HC + tid + 128];
    __syncthreads();
    float z = b1[tid];
#pragma unroll 8
    for (int k = 0; k < HC; k++) z += p[k] * w1[k * 128 + tid];
    z = fmaxf(z, 0.f);
    float t = z * w2[tid];
#pragma unroll
    for (int m = 32; m >= 1; m >>= 1) t += __shfl_xor(t, m);
    __shared__ float ws2[2];
    if ((tid & 63) == 0) ws2[tid >> 6] = t;
    __syncthreads();
    if (tid == 0) out[g] = ws2[0] + ws2[1] + b2[0];
}

// ---------------------------------------------------------------------------
// Host-side launcher
// ---------------------------------------------------------------------------
extern "C" void kernel_launch(void* const* d_in, const int* in_sizes, int n_in,
                              void* d_out, int out_size, void* d_ws, size_t ws_size,
                              hipStream_t stream) {
    const float* x      = (const float*)d_in[0];
    const int*   ei     = (const int*)d_in[1];
    const int*   batch  = (const int*)d_in[2];
    const float* W1     = (const float*)d_in[3];
    const float* as1    = (const float*)d_in[4];
    const float* ad1    = (const float*)d_in[5];
    const float* b1     = (const float*)d_in[6];
    const float* W2     = (const float*)d_in[7];
    const float* as2    = (const float*)d_in[8];
    const float* ad2    = (const float*)d_in[9];
    const float* b2     = (const float*)d_in[10];
    const float* lin1w  = (const float*)d_in[11];
    const float* lin1b  = (const float*)d_in[12];
    const float* lin2w  = (const float*)d_in[13];
    const float* lin2b  = (const float*)d_in[14];

    const int N   = in_sizes[2];       // 50000
    const int E   = in_sizes[1] / 2;   // 800000
    const int ET  = E + N;
    const int Fin = in_sizes[0] / N;   // 1280
    const int NG  = 64;

    const int nRB = (N + MR - 1) / MR;   // 1563 blocks of 32 rows
    const int nScanBlk = (N + 1023) / 1024;

    const int* src_arr = ei;
    const int* dst_arr = ei + E;

    char* ws = (char*)d_ws;
    size_t off = 0;
    auto alloc = [&](size_t bytes) {
        void* p = ws + off;
        off += (bytes + 255) & ~(size_t)255;
        return p;
    };
    float* h_agg   = (float*)alloc((size_t)N * HC * sizeof(float));
    u16*   hb_a    = (u16*)alloc((size_t)N * HC * sizeof(u16));
    u16*   hb_b    = (u16*)alloc((size_t)N * HC * sizeof(u16));
    float* a_src   = (float*)alloc((size_t)N * NH * sizeof(float));
    float* a_dst   = (float*)alloc((size_t)N * NH * sizeof(float));
    int*   deg     = (int*)alloc((size_t)N * sizeof(int));
    int*   cursor  = (int*)alloc((size_t)N * sizeof(int));
    int*   row_ptr = (int*)alloc((size_t)(N + 1) * sizeof(int));
    int*   partials= (int*)alloc((size_t)1024 * sizeof(int));
    int*   esrc    = (int*)alloc((size_t)ET * sizeof(int));
    float* pooled  = (float*)alloc((size_t)NG * HC * sizeof(float));
    u16* Bh = (u16*)alloc((size_t)Fin * HC * sizeof(u16));
    u16* Bl = (u16*)alloc((size_t)Fin * HC * sizeof(u16));
    (void)ws_size; (void)n_in; (void)out_size;

    // ---- CSR build ----
    hipMemsetAsync(deg, 0, (size_t)N * sizeof(int), stream);
    hipMemsetAsync(cursor, 0, (size_t)N * sizeof(int), stream);
    {
        const int blocks = (ET + 255) / 256;
        count_deg<<<blocks, 256, 0, stream>>>(dst_arr, E, ET, deg);
        scan_block<<<nScanBlk, 256, 0, stream>>>(deg, row_ptr, partials, N);
        scan_partials<<<1, 1024, 0, stream>>>(partials, nScanBlk);
        scan_add<<<(N + 255) / 256, 256, 0, stream>>>(row_ptr, partials, N);
        scatter_edges<<<blocks, 256, 0, stream>>>(src_arr, dst_arr, E, ET, row_ptr,
                                                  cursor, esrc);
    }

    const int aggBlocks = (N + 3) / 4;

    // ---- Layer 1 ----
    pack_b_split<<<(Fin / 32) * 4, 256, 0, stream>>>(W1, Fin, Bh, Bl);
    gemm_fused<float><<<nRB, 256, 0, stream>>>(x, Bh, Bl, as1, ad1,
                                               hb_a, a_src, a_dst, N, Fin);
    gat_aggregate_wave<u16><<<aggBlocks, 256, 0, stream>>>(hb_a, a_src, a_dst, row_ptr,
                                                           esrc, b1, hb_b, N);

    // ---- Layer 2 ----
    pack_b_split<<<(HC / 32) * 4, 256, 0, stream>>>(W2, HC, Bh, Bl);
    gemm_fused<u16><<<nRB, 256, 0, stream>>>(hb_b, Bh, Bl, as2, ad2,
                                             hb_a, a_src, a_dst, N, HC);
    gat_aggregate_wave<float><<<aggBlocks, 256, 0, stream>>>(hb_a, a_src, a_dst, row_ptr,
                                                             esrc, b2, h_agg, N);

    // ---- Pool + MLP head ----
    hipMemsetAsync(pooled, 0, (size_t)NG * HC * sizeof(float), stream);
    pool_partial<<<(N + 63) / 64, 256, 0, stream>>>(h_agg, batch, N, pooled);
    pool_div<<<NG, 256, 0, stream>>>(pooled, batch, N);
    mlp_head<<<NG, 128, 0, stream>>>(pooled, lin1w, lin1b, lin2w, lin2b, (float*)d_out);
}